// Round 3
// baseline (74961.768 us; speedup 1.0000x reference)
//
#include <hip/hip_runtime.h>
#include <stdint.h>
#include <math.h>

namespace {

constexpr int B = 256, L = 256, F = 38, H = 512, D = 512, Z = 16, NF = 20;
constexpr int NBLK = 512;           // persistent grid; 2 blocks/CU on 256 CUs
constexpr float LOG2PI_F = 1.8378770664093453f;
constexpr int LBZ = L * B * Z;
constexpr int HALF = LBZ / 2;
constexpr int HB = H * B;
constexpr int DB = D * B;
constexpr int ZB = Z * B;
constexpr int LFB = L * F * B;

// ---------------- math helpers ----------------

__device__ __forceinline__ float sigmoidf_(float x) {
  return 1.0f / (1.0f + expf(-x));
}
__device__ __forceinline__ float softplusf_(float x) {
  return fmaxf(x, 0.0f) + log1pf(expf(-fabsf(x)));
}

__device__ __forceinline__ void waveReduceAtomicAdd(float* dst, float v, int tid) {
  #pragma unroll
  for (int off = 32; off > 0; off >>= 1) v += __shfl_down(v, off, 64);
  if ((tid & 63) == 0) atomicAdd(dst, v);
}

// ---------------- threefry2x32 (JAX-compatible) ----------------

__host__ __device__ inline uint32_t rotl32_(uint32_t x, int d) {
  return (x << d) | (x >> (32 - d));
}

__host__ __device__ inline void threefry2x32_(uint32_t k0, uint32_t k1,
                                              uint32_t x0, uint32_t x1,
                                              uint32_t& o0, uint32_t& o1) {
  const uint32_t ks2 = k0 ^ k1 ^ 0x1BD11BDAu;
  uint32_t v0 = x0 + k0;
  uint32_t v1 = x1 + k1;
#define TF_RND(r) { v0 += v1; v1 = rotl32_(v1, r); v1 ^= v0; }
  TF_RND(13) TF_RND(15) TF_RND(26) TF_RND(6)
  v0 += k1;  v1 += ks2 + 1u;
  TF_RND(17) TF_RND(29) TF_RND(16) TF_RND(24)
  v0 += ks2; v1 += k0 + 2u;
  TF_RND(13) TF_RND(15) TF_RND(26) TF_RND(6)
  v0 += k0;  v1 += k1 + 3u;
  TF_RND(17) TF_RND(29) TF_RND(16) TF_RND(24)
  v0 += k1;  v1 += ks2 + 4u;
  TF_RND(13) TF_RND(15) TF_RND(26) TF_RND(6)
  v0 += ks2; v1 += k0 + 5u;
#undef TF_RND
  o0 = v0; o1 = v1;
}

__device__ __forceinline__ float erfinv_f_(float x) {
  float w = -log1pf(-x * x);
  float p;
  if (w < 5.0f) {
    w -= 2.5f;
    p = 2.81022636e-08f;
    p = fmaf(p, w, 3.43273939e-07f);
    p = fmaf(p, w, -3.5233877e-06f);
    p = fmaf(p, w, -4.39150654e-06f);
    p = fmaf(p, w, 0.00021858087f);
    p = fmaf(p, w, -0.00125372503f);
    p = fmaf(p, w, -0.00417768164f);
    p = fmaf(p, w, 0.246640727f);
    p = fmaf(p, w, 1.50140941f);
  } else {
    w = sqrtf(w) - 3.0f;
    p = -0.000200214257f;
    p = fmaf(p, w, 0.000100950558f);
    p = fmaf(p, w, 0.00134934322f);
    p = fmaf(p, w, -0.00367342844f);
    p = fmaf(p, w, 0.00573950773f);
    p = fmaf(p, w, -0.0076224613f);
    p = fmaf(p, w, 0.00943887047f);
    p = fmaf(p, w, 1.00167406f);
    p = fmaf(p, w, 2.83297682f);
  }
  return p * x;
}

__device__ __forceinline__ float bits_to_normal_(uint32_t bits) {
  uint32_t m = (bits >> 9) | 0x3f800000u;
  float f = __uint_as_float(m) - 1.0f;
  float u = f * 2.0f + (-0.99999994f);
  u = fmaxf(-0.99999994f, u);
  return 1.41421356f * erfinv_f_(u);
}

__device__ __forceinline__ float flows_dev(float zv[Z], const float* __restrict__ pu,
                                           const float* __restrict__ pw,
                                           const float* __restrict__ pb) {
  float ld = 0.0f;
  for (int f = 0; f < NF; ++f) {
    const float* w = pw + f * Z;
    const float* u = pu + f * Z;
    float wn2 = 0.0f, wu = 0.0f;
    #pragma unroll
    for (int i = 0; i < Z; ++i) { wn2 = fmaf(w[i], w[i], wn2); wu = fmaf(w[i], u[i], wu); }
    float coef = (softplusf_(wu) - 1.0f - wu) / wn2;
    float a_in = pb[f];
    #pragma unroll
    for (int i = 0; i < Z; ++i) a_in = fmaf(zv[i], w[i], a_in);
    float a = tanhf(a_in);
    float uw = 0.0f;
    #pragma unroll
    for (int i = 0; i < Z; ++i) {
      float uh = fmaf(coef, w[i], u[i]);
      uw = fmaf(uh, w[i], uw);
      zv[i] = fmaf(uh, a, zv[i]);
    }
    ld += logf(fabsf(1.0f + (1.0f - a * a) * uw) + 1e-12f);
  }
  return ld;
}

// ---------------- grid barrier (two-level, device scope) ----------------
// cnt layout (uints): sub[g] at cnt[g*16] for g=0..7 (64B apart); root at cnt[128].
__device__ __forceinline__ void gsync(unsigned* cnt, int bid, unsigned phase) {
  __syncthreads();
  if (threadIdx.x == 0) {
    const int g = bid >> 6;  // 8 groups of 64 blocks
    unsigned a = __hip_atomic_fetch_add(&cnt[g * 16], 1u, __ATOMIC_RELEASE,
                                        __HIP_MEMORY_SCOPE_AGENT);
    if (a + 1u == phase * 64u)
      __hip_atomic_fetch_add(&cnt[128], 1u, __ATOMIC_RELEASE,
                             __HIP_MEMORY_SCOPE_AGENT);
    while (__hip_atomic_load(&cnt[128], __ATOMIC_RELAXED,
                             __HIP_MEMORY_SCOPE_AGENT) < phase * 8u)
      __builtin_amdgcn_s_sleep(1);
  }
  __syncthreads();
  __builtin_amdgcn_fence(__ATOMIC_ACQUIRE, "agent");
}

// ---------------- stage device functions ----------------
// Tile: 8 rows x 64 batch cols; 4 waves split K; LDS cross-wave reduce.

template<bool THETA>
__device__ __forceinline__ void gru_stage(
    const float* __restrict__ xin, int K1, int w0h,
    const float* __restrict__ hT,
    const float* __restrict__ Wih, const float* __restrict__ Whh,
    const float* __restrict__ bih, const float* __restrict__ bhh,
    float* __restrict__ hout,
    float* __restrict__ zT_out,
    const float* __restrict__ pu, const float* __restrict__ pw,
    const float* __restrict__ pb, float* __restrict__ kld_acc,
    int rg, int bg, float* __restrict__ red_raw) {
  const int tid = threadIdx.x;
  const int lane = tid & 63;
  const int wv = __builtin_amdgcn_readfirstlane(tid >> 6);
  const int j0 = rg * 8;
  const int b0 = bg * 64;
  const int b = b0 + lane;

  float accR[8], accZ[8], accNX[8], accNH[8];
  #pragma unroll
  for (int r = 0; r < 8; ++r) { accR[r] = 0.f; accZ[r] = 0.f; accNX[r] = 0.f; accNH[r] = 0.f; }

  float zv[Z];
  float ld = 0.0f;

  if (wv == 0) {
    const float* wr = Wih + (size_t)(0 * H + j0) * K1;
    const float* wz = Wih + (size_t)(1 * H + j0) * K1;
    const float* wn = Wih + (size_t)(2 * H + j0) * K1;
    if (THETA) {
      #pragma unroll
      for (int i = 0; i < Z; ++i) zv[i] = xin[i * B + b];
      ld = flows_dev(zv, pu, pw, pb);
      #pragma unroll
      for (int k = 0; k < Z; ++k) {
        float a = zv[k];
        #pragma unroll
        for (int r = 0; r < 8; ++r) {
          accR[r]  = fmaf(wr[r * K1 + k], a, accR[r]);
          accZ[r]  = fmaf(wz[r * K1 + k], a, accZ[r]);
          accNX[r] = fmaf(wn[r * K1 + k], a, accNX[r]);
        }
      }
    } else {
      #pragma unroll 2
      for (int k = 0; k < K1; ++k) {
        float a = xin[k * B + b];
        #pragma unroll
        for (int r = 0; r < 8; ++r) {
          accR[r]  = fmaf(wr[r * K1 + k], a, accR[r]);
          accZ[r]  = fmaf(wz[r * K1 + k], a, accZ[r]);
          accNX[r] = fmaf(wn[r * K1 + k], a, accNX[r]);
        }
      }
    }
  }

  int hlo, hhi;
  {
    int rest = (H - w0h) / 3;
    if (wv == 0) { hlo = 0; hhi = w0h; }
    else { hlo = w0h + (wv - 1) * rest; hhi = hlo + rest; }
  }
  {
    const float* vr = Whh + (size_t)(0 * H + j0) * H;
    const float* vz = Whh + (size_t)(1 * H + j0) * H;
    const float* vn = Whh + (size_t)(2 * H + j0) * H;
    #pragma unroll 4
    for (int k = hlo; k < hhi; ++k) {
      float a = hT[k * B + b];
      #pragma unroll
      for (int r = 0; r < 8; ++r) {
        accR[r]  = fmaf(vr[r * H + k], a, accR[r]);
        accZ[r]  = fmaf(vz[r * H + k], a, accZ[r]);
        accNH[r] = fmaf(vn[r * H + k], a, accNH[r]);
      }
    }
  }

  float (*red)[4][8][64] = (float (*)[4][8][64])red_raw;
  #pragma unroll
  for (int r = 0; r < 8; ++r) {
    red[wv][0][r][lane] = accR[r];
    red[wv][1][r][lane] = accZ[r];
    red[wv][2][r][lane] = accNX[r];
    red[wv][3][r][lane] = accNH[r];
  }

  if (THETA) {
    if (wv == 0 && rg == 0) {
      #pragma unroll
      for (int i = 0; i < Z; ++i) zT_out[i * B + b] = zv[i];
      waveReduceAtomicAdd(kld_acc, -ld, lane);
    }
  }

  __syncthreads();

  #pragma unroll
  for (int it = tid; it < 512; it += 256) {
    int r = it >> 6, l = it & 63;
    float sR = 0.f, sZ = 0.f, sNX = 0.f, sNH = 0.f;
    #pragma unroll
    for (int w = 0; w < 4; ++w) {
      sR  += red[w][0][r][l];
      sZ  += red[w][1][r][l];
      sNX += red[w][2][r][l];
      sNH += red[w][3][r][l];
    }
    int j = j0 + r;
    int bb = b0 + l;
    float rg_ = sigmoidf_(sR + bih[j] + bhh[j]);
    float zg = sigmoidf_(sZ + bih[H + j] + bhh[H + j]);
    float ng = tanhf(sNX + bih[2 * H + j] + rg_ * (sNH + bhh[2 * H + j]));
    float hp = hT[(size_t)j * B + bb];
    hout[(size_t)j * B + bb] = (1.0f - zg) * ng + zg * hp;
  }
  __syncthreads();
}

__device__ __forceinline__ void lin_stage(
    const float* __restrict__ A1, int K1,
    const float* __restrict__ A2, int K2,
    const float* __restrict__ W, const float* __restrict__ bias,
    float* __restrict__ outp, int relu,
    int rg, int bg, float* __restrict__ red_raw) {
  const int tid = threadIdx.x;
  const int lane = tid & 63;
  const int wv = __builtin_amdgcn_readfirstlane(tid >> 6);
  const int r0 = rg * 8;
  const int b0 = bg * 64;
  const int b = b0 + lane;
  const int Kv = K1 + K2;
  const int klo = wv * (Kv >> 2);
  const int khi = klo + (Kv >> 2);

  float acc[8];
  #pragma unroll
  for (int r = 0; r < 8; ++r) acc[r] = 0.f;

  const float* wbase = W + (size_t)r0 * Kv;
  {
    int lo = klo, hi = khi < K1 ? khi : K1;
    #pragma unroll 4
    for (int k = lo; k < hi; ++k) {
      float a = A1[(size_t)k * B + b];
      #pragma unroll
      for (int r = 0; r < 8; ++r) acc[r] = fmaf(wbase[(size_t)r * Kv + k], a, acc[r]);
    }
  }
  if (K2 > 0) {
    int lo = klo > K1 ? klo : K1, hi = khi;
    for (int k = lo; k < hi; ++k) {
      float a = A2[(size_t)(k - K1) * B + b];
      #pragma unroll
      for (int r = 0; r < 8; ++r) acc[r] = fmaf(wbase[(size_t)r * Kv + k], a, acc[r]);
    }
  }

  float (*red)[8][64] = (float (*)[8][64])red_raw;
  #pragma unroll
  for (int r = 0; r < 8; ++r) red[wv][r][lane] = acc[r];
  __syncthreads();

  #pragma unroll
  for (int it = tid; it < 512; it += 256) {
    int r = it >> 6, l = it & 63;
    float s = red[0][r][l] + red[1][r][l] + red[2][r][l] + red[3][r][l] + bias[r0 + r];
    if (relu) s = fmaxf(s, 0.f);
    outp[(size_t)(r0 + r) * B + b0 + l] = s;
  }
  __syncthreads();
}

__device__ __forceinline__ void zhead_stage(
    const float* __restrict__ h2T,
    const float* __restrict__ zlocW, const float* __restrict__ zlocb,
    const float* __restrict__ zscaleW, const float* __restrict__ zscaleb,
    const float* __restrict__ eps_t,
    float* __restrict__ z0T, float* __restrict__ kld_acc,
    int zq, int bg, float* __restrict__ red_raw) {
  const int tid = threadIdx.x;
  const int lane = tid & 63;
  const int wv = __builtin_amdgcn_readfirstlane(tid >> 6);
  const int z0q = zq * 4;
  const int b0 = bg * 64;
  const int b = b0 + lane;
  const int klo = wv * (D >> 2), khi = klo + (D >> 2);

  const float* wp[8];
  #pragma unroll
  for (int i = 0; i < 8; ++i) {
    int zz = z0q + (i >> 1);
    wp[i] = ((i & 1) ? zscaleW : zlocW) + (size_t)zz * D;
  }
  float acc[8];
  #pragma unroll
  for (int i = 0; i < 8; ++i) acc[i] = 0.f;
  #pragma unroll 4
  for (int k = klo; k < khi; ++k) {
    float a = h2T[(size_t)k * B + b];
    #pragma unroll
    for (int i = 0; i < 8; ++i) acc[i] = fmaf(wp[i][k], a, acc[i]);
  }

  float (*red)[8][64] = (float (*)[8][64])red_raw;
  #pragma unroll
  for (int i = 0; i < 8; ++i) red[wv][i][lane] = acc[i];
  __syncthreads();

  int zi = tid >> 6, l = tid & 63;
  int zz = z0q + zi;
  int bb = b0 + l;
  float sl = red[0][2 * zi][l] + red[1][2 * zi][l] + red[2][2 * zi][l] + red[3][2 * zi][l]
             + zlocb[zz];
  float ss = red[0][2 * zi + 1][l] + red[1][2 * zi + 1][l] + red[2][2 * zi + 1][l]
             + red[3][2 * zi + 1][l] + zscaleb[zz];
  float scale = softplusf_(ss) + 1e-6f;
  float ez = eps_t[bb * Z + zz];
  z0T[zz * B + bb] = sl + scale * ez;
  waveReduceAtomicAdd(kld_acc, -logf(scale), tid);
  __syncthreads();
}

__device__ __forceinline__ void yhead_stage(
    const float* __restrict__ g2T,
    const float* __restrict__ xlocW, const float* __restrict__ xlocb,
    const float* __restrict__ xscaleW, const float* __restrict__ xscaleb,
    const float* __restrict__ xT, int t,
    float* __restrict__ out_yloc, float* __restrict__ recon_acc,
    int fq, int bg, float* __restrict__ red_raw) {
  const int tid = threadIdx.x;
  const int lane = tid & 63;
  const int wv = __builtin_amdgcn_readfirstlane(tid >> 6);
  const int f0 = fq * 4;
  const int b0 = bg * 64;
  const int b = b0 + lane;
  const int klo = wv * (D >> 2), khi = klo + (D >> 2);

  const float* wp[8];
  #pragma unroll
  for (int i = 0; i < 8; ++i) {
    int ff = f0 + (i >> 1);
    int fc = ff < F ? ff : 0;
    wp[i] = ((i & 1) ? xscaleW : xlocW) + (size_t)fc * D;
  }
  float acc[8];
  #pragma unroll
  for (int i = 0; i < 8; ++i) acc[i] = 0.f;
  #pragma unroll 4
  for (int k = klo; k < khi; ++k) {
    float a = g2T[(size_t)k * B + b];
    #pragma unroll
    for (int i = 0; i < 8; ++i) acc[i] = fmaf(wp[i][k], a, acc[i]);
  }

  float (*red)[8][64] = (float (*)[8][64])red_raw;
  #pragma unroll
  for (int i = 0; i < 8; ++i) red[wv][i][lane] = acc[i];
  __syncthreads();

  int fi = tid >> 6, l = tid & 63;
  int ff = f0 + fi;
  int bb = b0 + l;
  float nl = 0.0f;
  if (ff < F) {
    float loc = red[0][2 * fi][l] + red[1][2 * fi][l] + red[2][2 * fi][l] + red[3][2 * fi][l]
                + xlocb[ff];
    float sp = red[0][2 * fi + 1][l] + red[1][2 * fi + 1][l] + red[2][2 * fi + 1][l]
               + red[3][2 * fi + 1][l] + xscaleb[ff];
    float scale = softplusf_(sp) + 1e-6f;
    out_yloc[((size_t)bb * L + t) * F + ff] = loc;
    float xv = xT[((size_t)t * F + ff) * B + bb];
    float d = (xv - loc) / scale;
    nl = 0.5f * d * d + logf(scale) + 0.5f * LOG2PI_F;
  }
  waveReduceAtomicAdd(recon_acc, nl, tid);
  __syncthreads();
}

// ---------------- setup kernels ----------------

__global__ __launch_bounds__(256) void k_transpose_x(const float* __restrict__ x,
                                                     float* __restrict__ xT) {
  int idx = blockIdx.x * blockDim.x + threadIdx.x;
  int f = idx % F;
  int t = (idx / F) % L;
  int b = idx / (F * L);
  xT[(t * F + f) * B + b] = x[idx];
}

__global__ __launch_bounds__(256) void k_noise(float* __restrict__ eps_z,
                                               float* __restrict__ kld_acc,
                                               uint32_t kz0, uint32_t kz1,
                                               uint32_t kp0, uint32_t kp1) {
  int i = blockIdx.x * blockDim.x + threadIdx.x;
  uint32_t a0, a1, b0, b1;
  threefry2x32_(kz0, kz1, (uint32_t)i, (uint32_t)(i + HALF), a0, a1);
  float ez0 = bits_to_normal_(a0);
  float ez1 = bits_to_normal_(a1);
  eps_z[i] = ez0;
  eps_z[i + HALF] = ez1;
  threefry2x32_(kp0, kp1, (uint32_t)i, (uint32_t)(i + HALF), b0, b1);
  float ep0 = bits_to_normal_(b0);
  float ep1 = bits_to_normal_(b1);
  float local = -0.5f * (ez0 * ez0 + ez1 * ez1) + 0.5f * (ep0 * ep0 + ep1 * ep1);
  waveReduceAtomicAdd(kld_acc, local, threadIdx.x);
}

// ---------------- the persistent kernel ----------------

__global__ __launch_bounds__(256, 2) void k_persist(
    const float* __restrict__ xT, const float* __restrict__ eps_z,
    const float* __restrict__ phi_Wih, const float* __restrict__ phi_Whh,
    const float* __restrict__ phi_bih, const float* __restrict__ phi_bhh,
    const float* __restrict__ phi_W1, const float* __restrict__ phi_b1,
    const float* __restrict__ phi_W2, const float* __restrict__ phi_b2,
    const float* __restrict__ zloc_W, const float* __restrict__ zloc_b,
    const float* __restrict__ zscale_W, const float* __restrict__ zscale_b,
    const float* __restrict__ pu, const float* __restrict__ pw,
    const float* __restrict__ pb,
    const float* __restrict__ th_Wih, const float* __restrict__ th_Whh,
    const float* __restrict__ th_bih, const float* __restrict__ th_bhh,
    const float* __restrict__ th_W1, const float* __restrict__ th_b1,
    const float* __restrict__ th_W2, const float* __restrict__ th_b2,
    const float* __restrict__ xloc_W, const float* __restrict__ xloc_b,
    const float* __restrict__ xscale_W, const float* __restrict__ xscale_b,
    float* __restrict__ out, float* __restrict__ acc,
    float* __restrict__ bufp0, float* __restrict__ bufp1,
    float* __restrict__ buft0, float* __restrict__ buft1,
    float* __restrict__ zT, float* __restrict__ z0,
    float* __restrict__ h1p, float* __restrict__ h2p,
    float* __restrict__ g1t, float* __restrict__ g2t,
    unsigned* __restrict__ cnt) {
  __shared__ float red[4 * 4 * 8 * 64];  // 32 KB, reused by all stages
  const int bid = blockIdx.x;
  const bool th = bid >= 256;
  const int sb = th ? bid - 256 : bid;
  const int rg = sb >> 2, bg = sb & 3;
  float* bufp[2] = {bufp0, bufp1};
  float* buft[2] = {buft0, buft1};
  unsigned phase = 0;

  for (int i = 0; i <= L; ++i) {
    // ---- interval A: phiGRU(i) || thetaGRU(i-1)+flows ----
    if (!th) {
      if (i < L)
        gru_stage<false>(xT + (size_t)i * F * B, F, 101, bufp[i & 1],
                         phi_Wih, phi_Whh, phi_bih, phi_bhh, bufp[(i + 1) & 1],
                         nullptr, nullptr, nullptr, nullptr, nullptr, rg, bg, red);
    } else if (i > 0) {
      gru_stage<true>(z0, Z, 44, buft[(i - 1) & 1],
                      th_Wih, th_Whh, th_bih, th_bhh, buft[i & 1],
                      zT, pu, pw, pb, acc, rg, bg, red);
    }
    gsync(cnt, bid, ++phase);

    // ---- interval B: phiMLP1(i) || thetaW1(i-1) ----
    if (!th) {
      if (i < L)
        lin_stage(bufp[(i + 1) & 1], H, zT, Z, phi_W1, phi_b1, h1p, 1, rg, bg, red);
    } else if (i > 0) {
      lin_stage(buft[i & 1], H, nullptr, 0, th_W1, th_b1, g1t, 1, rg, bg, red);
    }
    gsync(cnt, bid, ++phase);

    // ---- interval C: phiMLP2(i) || thetaW2(i-1) ----
    if (!th) {
      if (i < L)
        lin_stage(h1p, D, nullptr, 0, phi_W2, phi_b2, h2p, 0, rg, bg, red);
    } else if (i > 0) {
      lin_stage(g1t, D, nullptr, 0, th_W2, th_b2, g2t, 0, rg, bg, red);
    }
    gsync(cnt, bid, ++phase);

    // ---- interval D: zhead(i) || yhead(i-1) ----
    if (!th) {
      if (i < L && sb < 16)
        zhead_stage(h2p, zloc_W, zloc_b, zscale_W, zscale_b,
                    eps_z + (size_t)i * B * Z, z0, acc, sb >> 2, sb & 3, red);
    } else if (i > 0 && sb < 40) {
      yhead_stage(g2t, xloc_W, xloc_b, xscale_W, xscale_b, xT, i - 1,
                  out, acc + 1, sb >> 2, sb & 3, red);
    }
    gsync(cnt, bid, ++phase);
  }

  if (bid == 0 && threadIdx.x == 0) {
    out[(size_t)LFB]     = __hip_atomic_load(acc + 1, __ATOMIC_RELAXED,
                                             __HIP_MEMORY_SCOPE_AGENT);
    out[(size_t)LFB + 1] = __hip_atomic_load(acc, __ATOMIC_RELAXED,
                                             __HIP_MEMORY_SCOPE_AGENT);
  }
}

}  // namespace

extern "C" void kernel_launch(void* const* d_in, const int* in_sizes, int n_in,
                              void* d_out, int out_size, void* d_ws, size_t ws_size,
                              hipStream_t stream) {
  const float* x        = (const float*)d_in[0];
  const float* phi_Wih  = (const float*)d_in[1];
  const float* phi_Whh  = (const float*)d_in[2];
  const float* phi_bih  = (const float*)d_in[3];
  const float* phi_bhh  = (const float*)d_in[4];
  const float* phi_W1   = (const float*)d_in[5];
  const float* phi_b1   = (const float*)d_in[6];
  const float* phi_W2   = (const float*)d_in[7];
  const float* phi_b2   = (const float*)d_in[8];
  const float* zloc_W   = (const float*)d_in[9];
  const float* zloc_b   = (const float*)d_in[10];
  const float* zscale_W = (const float*)d_in[11];
  const float* zscale_b = (const float*)d_in[12];
  const float* pu       = (const float*)d_in[13];
  const float* pw       = (const float*)d_in[14];
  const float* pb       = (const float*)d_in[15];
  const float* th_Wih   = (const float*)d_in[16];
  const float* th_Whh   = (const float*)d_in[17];
  const float* th_bih   = (const float*)d_in[18];
  const float* th_bhh   = (const float*)d_in[19];
  const float* th_W1    = (const float*)d_in[20];
  const float* th_b1    = (const float*)d_in[21];
  const float* th_W2    = (const float*)d_in[22];
  const float* th_b2    = (const float*)d_in[23];
  const float* xloc_W   = (const float*)d_in[24];
  const float* xloc_b   = (const float*)d_in[25];
  const float* xscale_W = (const float*)d_in[26];
  const float* xscale_b = (const float*)d_in[27];

  float* out = (float*)d_out;
  float* ws = (float*)d_ws;

  // workspace layout (floats)
  unsigned* cnt = (unsigned*)ws;        // 256 uints (two-level barrier counters)
  float* acc    = ws + 256;             // [0]=kld, [1]=recon
  float* eps_z  = ws + 320;             // LBZ
  float* xT     = eps_z + LBZ;          // LFB
  float* bufp0  = xT + LFB;             // HB   (zero-init: h_phi(-1))
  float* buft0  = bufp0 + HB;           // HB   (zero-init: h_theta(-1))
  float* zT     = buft0 + HB;           // ZB   (zero-init: z(-1))
  float* bufp1  = zT + ZB;              // HB
  float* buft1  = bufp1 + HB;           // HB
  float* z0     = buft1 + HB;           // ZB
  float* h1p    = z0 + ZB;              // DB
  float* h2p    = h1p + DB;             // DB
  float* g1t    = h2p + DB;             // DB
  float* g2t    = g1t + DB;             // DB

  hipMemsetAsync(cnt, 0, 1024 + 64 * sizeof(float), stream);           // counters + acc pad
  hipMemsetAsync(bufp0, 0, (size_t)(2 * HB + ZB) * sizeof(float), stream);

  uint32_t a0, a1, b0, b1;
  threefry2x32_(0u, 42u, 0u, 2u, a0, a1);
  threefry2x32_(0u, 42u, 1u, 3u, b0, b1);
  const uint32_t kz0 = a0, kz1 = b0, kp0 = a1, kp1 = b1;

  k_transpose_x<<<(B * L * F) / 256, 256, 0, stream>>>(x, xT);
  k_noise<<<HALF / 256, 256, 0, stream>>>(eps_z, acc, kz0, kz1, kp0, kp1);

  k_persist<<<NBLK, 256, 0, stream>>>(
      xT, eps_z,
      phi_Wih, phi_Whh, phi_bih, phi_bhh, phi_W1, phi_b1, phi_W2, phi_b2,
      zloc_W, zloc_b, zscale_W, zscale_b, pu, pw, pb,
      th_Wih, th_Whh, th_bih, th_bhh, th_W1, th_b1, th_W2, th_b2,
      xloc_W, xloc_b, xscale_W, xscale_b,
      out, acc, bufp0, bufp1, buft0, buft1, zT, z0, h1p, h2p, g1t, g2t, cnt);
}

// Round 4
// 45793.796 us; speedup vs baseline: 1.6369x; 1.6369x over previous
//
#include <hip/hip_runtime.h>
#include <stdint.h>
#include <math.h>

namespace {

constexpr int B = 256, L = 256, F = 38, H = 512, D = 512, Z = 16, NF = 20;
constexpr int NBLK = 512;           // persistent grid; 2 blocks/CU on 256 CUs
constexpr float LOG2PI_F = 1.8378770664093453f;
constexpr int LBZ = L * B * Z;
constexpr int HALF = LBZ / 2;
constexpr int HB = H * B;
constexpr int DB = D * B;
constexpr int ZB = Z * B;
constexpr int LFB = L * F * B;

// ---------------- math helpers ----------------

__device__ __forceinline__ float sigmoidf_(float x) {
  return 1.0f / (1.0f + expf(-x));
}
__device__ __forceinline__ float softplusf_(float x) {
  return fmaxf(x, 0.0f) + log1pf(expf(-fabsf(x)));
}

// Cross-XCD coherent access: relaxed agent-scope atomics compile to
// global_load/store with sc0 sc1 (bypass L1/L2, served at MALL). This keeps
// weights L2-cached (no buffer_inv per barrier — round 3's 12.7 GB refetch).
__device__ __forceinline__ float gload(const float* p) {
  return __hip_atomic_load(p, __ATOMIC_RELAXED, __HIP_MEMORY_SCOPE_AGENT);
}
__device__ __forceinline__ void gstore(float* p, float v) {
  __hip_atomic_store(p, v, __ATOMIC_RELAXED, __HIP_MEMORY_SCOPE_AGENT);
}
__device__ __forceinline__ void gAtomicAdd(float* p, float v) {
  __hip_atomic_fetch_add(p, v, __ATOMIC_RELAXED, __HIP_MEMORY_SCOPE_AGENT);
}

__device__ __forceinline__ void waveReduceAtomicAdd(float* dst, float v, int tid) {
  #pragma unroll
  for (int off = 32; off > 0; off >>= 1) v += __shfl_down(v, off, 64);
  if ((tid & 63) == 0) gAtomicAdd(dst, v);
}

// ---------------- threefry2x32 (JAX-compatible) ----------------

__host__ __device__ inline uint32_t rotl32_(uint32_t x, int d) {
  return (x << d) | (x >> (32 - d));
}

__host__ __device__ inline void threefry2x32_(uint32_t k0, uint32_t k1,
                                              uint32_t x0, uint32_t x1,
                                              uint32_t& o0, uint32_t& o1) {
  const uint32_t ks2 = k0 ^ k1 ^ 0x1BD11BDAu;
  uint32_t v0 = x0 + k0;
  uint32_t v1 = x1 + k1;
#define TF_RND(r) { v0 += v1; v1 = rotl32_(v1, r); v1 ^= v0; }
  TF_RND(13) TF_RND(15) TF_RND(26) TF_RND(6)
  v0 += k1;  v1 += ks2 + 1u;
  TF_RND(17) TF_RND(29) TF_RND(16) TF_RND(24)
  v0 += ks2; v1 += k0 + 2u;
  TF_RND(13) TF_RND(15) TF_RND(26) TF_RND(6)
  v0 += k0;  v1 += k1 + 3u;
  TF_RND(17) TF_RND(29) TF_RND(16) TF_RND(24)
  v0 += k1;  v1 += ks2 + 4u;
  TF_RND(13) TF_RND(15) TF_RND(26) TF_RND(6)
  v0 += ks2; v1 += k0 + 5u;
#undef TF_RND
  o0 = v0; o1 = v1;
}

__device__ __forceinline__ float erfinv_f_(float x) {
  float w = -log1pf(-x * x);
  float p;
  if (w < 5.0f) {
    w -= 2.5f;
    p = 2.81022636e-08f;
    p = fmaf(p, w, 3.43273939e-07f);
    p = fmaf(p, w, -3.5233877e-06f);
    p = fmaf(p, w, -4.39150654e-06f);
    p = fmaf(p, w, 0.00021858087f);
    p = fmaf(p, w, -0.00125372503f);
    p = fmaf(p, w, -0.00417768164f);
    p = fmaf(p, w, 0.246640727f);
    p = fmaf(p, w, 1.50140941f);
  } else {
    w = sqrtf(w) - 3.0f;
    p = -0.000200214257f;
    p = fmaf(p, w, 0.000100950558f);
    p = fmaf(p, w, 0.00134934322f);
    p = fmaf(p, w, -0.00367342844f);
    p = fmaf(p, w, 0.00573950773f);
    p = fmaf(p, w, -0.0076224613f);
    p = fmaf(p, w, 0.00943887047f);
    p = fmaf(p, w, 1.00167406f);
    p = fmaf(p, w, 2.83297682f);
  }
  return p * x;
}

__device__ __forceinline__ float bits_to_normal_(uint32_t bits) {
  uint32_t m = (bits >> 9) | 0x3f800000u;
  float f = __uint_as_float(m) - 1.0f;
  float u = f * 2.0f + (-0.99999994f);
  u = fmaxf(-0.99999994f, u);
  return 1.41421356f * erfinv_f_(u);
}

__device__ __forceinline__ float flows_dev(float zv[Z], const float* __restrict__ pu,
                                           const float* __restrict__ pw,
                                           const float* __restrict__ pb) {
  float ld = 0.0f;
  for (int f = 0; f < NF; ++f) {
    const float* w = pw + f * Z;
    const float* u = pu + f * Z;
    float wn2 = 0.0f, wu = 0.0f;
    #pragma unroll
    for (int i = 0; i < Z; ++i) { wn2 = fmaf(w[i], w[i], wn2); wu = fmaf(w[i], u[i], wu); }
    float coef = (softplusf_(wu) - 1.0f - wu) / wn2;
    float a_in = pb[f];
    #pragma unroll
    for (int i = 0; i < Z; ++i) a_in = fmaf(zv[i], w[i], a_in);
    float a = tanhf(a_in);
    float uw = 0.0f;
    #pragma unroll
    for (int i = 0; i < Z; ++i) {
      float uh = fmaf(coef, w[i], u[i]);
      uw = fmaf(uh, w[i], uw);
      zv[i] = fmaf(uh, a, zv[i]);
    }
    ld += logf(fabsf(1.0f + (1.0f - a * a) * uw) + 1e-12f);
  }
  return ld;
}

// ---------------- grid barrier (two-level, agent scope, NO cache inv) ------
__device__ __forceinline__ void gsync(unsigned* cnt, int bid, unsigned phase) {
  __syncthreads();  // drains vmcnt(0): all sc0sc1 stores are at the MALL
  if (threadIdx.x == 0) {
    const int g = bid >> 6;  // 8 groups of 64 blocks
    unsigned a = __hip_atomic_fetch_add(&cnt[g * 16], 1u, __ATOMIC_RELEASE,
                                        __HIP_MEMORY_SCOPE_AGENT);
    if (a + 1u == phase * 64u)
      __hip_atomic_fetch_add(&cnt[128], 1u, __ATOMIC_RELEASE,
                             __HIP_MEMORY_SCOPE_AGENT);
    while (__hip_atomic_load(&cnt[128], __ATOMIC_RELAXED,
                             __HIP_MEMORY_SCOPE_AGENT) < phase * 8u)
      __builtin_amdgcn_s_sleep(2);
  }
  __syncthreads();
}

// ---------------- stage device functions ----------------
// Tile: 8 rows x 64 batch cols; 4 waves split K; LDS cross-wave reduce.
// Activations (cross-barrier) via gload/gstore; weights via plain cached loads.

template<bool THETA>
__device__ __forceinline__ void gru_stage(
    const float* __restrict__ xin, int K1, int w0h,
    const float* __restrict__ hT,
    const float* __restrict__ Wih, const float* __restrict__ Whh,
    const float* __restrict__ bih, const float* __restrict__ bhh,
    float* __restrict__ hout,
    float* __restrict__ zT_out,
    const float* __restrict__ pu, const float* __restrict__ pw,
    const float* __restrict__ pb, float* __restrict__ kld_acc,
    int rg, int bg, float* __restrict__ red_raw) {
  const int tid = threadIdx.x;
  const int lane = tid & 63;
  const int wv = __builtin_amdgcn_readfirstlane(tid >> 6);
  const int j0 = rg * 8;
  const int b0 = bg * 64;
  const int b = b0 + lane;

  float accR[8], accZ[8], accNX[8], accNH[8];
  #pragma unroll
  for (int r = 0; r < 8; ++r) { accR[r] = 0.f; accZ[r] = 0.f; accNX[r] = 0.f; accNH[r] = 0.f; }

  float zv[Z];
  float ld = 0.0f;

  if (wv == 0) {
    const float* wr = Wih + (size_t)(0 * H + j0) * K1;
    const float* wz = Wih + (size_t)(1 * H + j0) * K1;
    const float* wn = Wih + (size_t)(2 * H + j0) * K1;
    if (THETA) {
      #pragma unroll
      for (int i = 0; i < Z; ++i) zv[i] = gload(&xin[i * B + b]);
      ld = flows_dev(zv, pu, pw, pb);
      #pragma unroll
      for (int k = 0; k < Z; ++k) {
        float a = zv[k];
        #pragma unroll
        for (int r = 0; r < 8; ++r) {
          accR[r]  = fmaf(wr[r * K1 + k], a, accR[r]);
          accZ[r]  = fmaf(wz[r * K1 + k], a, accZ[r]);
          accNX[r] = fmaf(wn[r * K1 + k], a, accNX[r]);
        }
      }
    } else {
      #pragma unroll 2
      for (int k = 0; k < K1; ++k) {
        float a = xin[k * B + b];  // xT: immutable input, cached
        #pragma unroll
        for (int r = 0; r < 8; ++r) {
          accR[r]  = fmaf(wr[r * K1 + k], a, accR[r]);
          accZ[r]  = fmaf(wz[r * K1 + k], a, accZ[r]);
          accNX[r] = fmaf(wn[r * K1 + k], a, accNX[r]);
        }
      }
    }
  }

  int hlo, hhi;
  {
    int rest = (H - w0h) / 3;
    if (wv == 0) { hlo = 0; hhi = w0h; }
    else { hlo = w0h + (wv - 1) * rest; hhi = hlo + rest; }
  }
  {
    const float* vr = Whh + (size_t)(0 * H + j0) * H;
    const float* vz = Whh + (size_t)(1 * H + j0) * H;
    const float* vn = Whh + (size_t)(2 * H + j0) * H;
    #pragma unroll 4
    for (int k = hlo; k < hhi; ++k) {
      float a = gload(&hT[k * B + b]);
      #pragma unroll
      for (int r = 0; r < 8; ++r) {
        accR[r]  = fmaf(vr[r * H + k], a, accR[r]);
        accZ[r]  = fmaf(vz[r * H + k], a, accZ[r]);
        accNH[r] = fmaf(vn[r * H + k], a, accNH[r]);
      }
    }
  }

  float (*red)[4][8][64] = (float (*)[4][8][64])red_raw;
  #pragma unroll
  for (int r = 0; r < 8; ++r) {
    red[wv][0][r][lane] = accR[r];
    red[wv][1][r][lane] = accZ[r];
    red[wv][2][r][lane] = accNX[r];
    red[wv][3][r][lane] = accNH[r];
  }

  if (THETA) {
    if (wv == 0 && rg == 0) {
      #pragma unroll
      for (int i = 0; i < Z; ++i) gstore(&zT_out[i * B + b], zv[i]);
      waveReduceAtomicAdd(kld_acc, -ld, lane);
    }
  }

  __syncthreads();

  #pragma unroll
  for (int it = tid; it < 512; it += 256) {
    int r = it >> 6, l = it & 63;
    float sR = 0.f, sZ = 0.f, sNX = 0.f, sNH = 0.f;
    #pragma unroll
    for (int w = 0; w < 4; ++w) {
      sR  += red[w][0][r][l];
      sZ  += red[w][1][r][l];
      sNX += red[w][2][r][l];
      sNH += red[w][3][r][l];
    }
    int j = j0 + r;
    int bb = b0 + l;
    float rg_ = sigmoidf_(sR + bih[j] + bhh[j]);
    float zg = sigmoidf_(sZ + bih[H + j] + bhh[H + j]);
    float ng = tanhf(sNX + bih[2 * H + j] + rg_ * (sNH + bhh[2 * H + j]));
    float hp = gload(&hT[(size_t)j * B + bb]);
    gstore(&hout[(size_t)j * B + bb], (1.0f - zg) * ng + zg * hp);
  }
  __syncthreads();
}

__device__ __forceinline__ void lin_stage(
    const float* __restrict__ A1, int K1,
    const float* __restrict__ A2, int K2,
    const float* __restrict__ W, const float* __restrict__ bias,
    float* __restrict__ outp, int relu,
    int rg, int bg, float* __restrict__ red_raw) {
  const int tid = threadIdx.x;
  const int lane = tid & 63;
  const int wv = __builtin_amdgcn_readfirstlane(tid >> 6);
  const int r0 = rg * 8;
  const int b0 = bg * 64;
  const int b = b0 + lane;
  const int Kv = K1 + K2;
  const int klo = wv * (Kv >> 2);
  const int khi = klo + (Kv >> 2);

  float acc[8];
  #pragma unroll
  for (int r = 0; r < 8; ++r) acc[r] = 0.f;

  const float* wbase = W + (size_t)r0 * Kv;
  {
    int lo = klo, hi = khi < K1 ? khi : K1;
    #pragma unroll 4
    for (int k = lo; k < hi; ++k) {
      float a = gload(&A1[(size_t)k * B + b]);
      #pragma unroll
      for (int r = 0; r < 8; ++r) acc[r] = fmaf(wbase[(size_t)r * Kv + k], a, acc[r]);
    }
  }
  if (K2 > 0) {
    int lo = klo > K1 ? klo : K1, hi = khi;
    for (int k = lo; k < hi; ++k) {
      float a = gload(&A2[(size_t)(k - K1) * B + b]);
      #pragma unroll
      for (int r = 0; r < 8; ++r) acc[r] = fmaf(wbase[(size_t)r * Kv + k], a, acc[r]);
    }
  }

  float (*red)[8][64] = (float (*)[8][64])red_raw;
  #pragma unroll
  for (int r = 0; r < 8; ++r) red[wv][r][lane] = acc[r];
  __syncthreads();

  #pragma unroll
  for (int it = tid; it < 512; it += 256) {
    int r = it >> 6, l = it & 63;
    float s = red[0][r][l] + red[1][r][l] + red[2][r][l] + red[3][r][l] + bias[r0 + r];
    if (relu) s = fmaxf(s, 0.f);
    gstore(&outp[(size_t)(r0 + r) * B + b0 + l], s);
  }
  __syncthreads();
}

// z head fused with phi_W2: reads h1 (K=512) against precomputed A_z [32][512]
__device__ __forceinline__ void zhead_stage(
    const float* __restrict__ h1T,
    const float* __restrict__ Az, const float* __restrict__ cz,
    const float* __restrict__ eps_t,
    float* __restrict__ z0T, float* __restrict__ kld_acc,
    int zq, int bg, float* __restrict__ red_raw) {
  const int tid = threadIdx.x;
  const int lane = tid & 63;
  const int wv = __builtin_amdgcn_readfirstlane(tid >> 6);
  const int z0q = zq * 4;
  const int b0 = bg * 64;
  const int b = b0 + lane;
  const int klo = wv * (D >> 2), khi = klo + (D >> 2);

  const float* wp[8];
  #pragma unroll
  for (int i = 0; i < 8; ++i) {
    int zz = z0q + (i >> 1);
    wp[i] = Az + (size_t)(((i & 1) ? Z + zz : zz)) * D;
  }
  float acc[8];
  #pragma unroll
  for (int i = 0; i < 8; ++i) acc[i] = 0.f;
  #pragma unroll 4
  for (int k = klo; k < khi; ++k) {
    float a = gload(&h1T[(size_t)k * B + b]);
    #pragma unroll
    for (int i = 0; i < 8; ++i) acc[i] = fmaf(wp[i][k], a, acc[i]);
  }

  float (*red)[8][64] = (float (*)[8][64])red_raw;
  #pragma unroll
  for (int i = 0; i < 8; ++i) red[wv][i][lane] = acc[i];
  __syncthreads();

  int zi = tid >> 6, l = tid & 63;
  int zz = z0q + zi;
  int bb = b0 + l;
  float sl = red[0][2 * zi][l] + red[1][2 * zi][l] + red[2][2 * zi][l] + red[3][2 * zi][l]
             + cz[zz];
  float ss = red[0][2 * zi + 1][l] + red[1][2 * zi + 1][l] + red[2][2 * zi + 1][l]
             + red[3][2 * zi + 1][l] + cz[Z + zz];
  float scale = softplusf_(ss) + 1e-6f;
  float ez = eps_t[bb * Z + zz];
  gstore(&z0T[zz * B + bb], sl + scale * ez);
  waveReduceAtomicAdd(kld_acc, -logf(scale), tid);
  __syncthreads();
}

// y head fused with th_W2: reads g1 (K=512) against precomputed A_y [76][512]
__device__ __forceinline__ void yhead_stage(
    const float* __restrict__ g1T,
    const float* __restrict__ Ay, const float* __restrict__ cy,
    const float* __restrict__ xT, int t,
    float* __restrict__ out_yloc, float* __restrict__ recon_acc,
    int fq, int bg, float* __restrict__ red_raw) {
  const int tid = threadIdx.x;
  const int lane = tid & 63;
  const int wv = __builtin_amdgcn_readfirstlane(tid >> 6);
  const int f0 = fq * 4;
  const int b0 = bg * 64;
  const int b = b0 + lane;
  const int klo = wv * (D >> 2), khi = klo + (D >> 2);

  const float* wp[8];
  #pragma unroll
  for (int i = 0; i < 8; ++i) {
    int ff = f0 + (i >> 1);
    int fc = ff < F ? ff : 0;
    wp[i] = Ay + (size_t)(((i & 1) ? F + fc : fc)) * D;
  }
  float acc[8];
  #pragma unroll
  for (int i = 0; i < 8; ++i) acc[i] = 0.f;
  #pragma unroll 4
  for (int k = klo; k < khi; ++k) {
    float a = gload(&g1T[(size_t)k * B + b]);
    #pragma unroll
    for (int i = 0; i < 8; ++i) acc[i] = fmaf(wp[i][k], a, acc[i]);
  }

  float (*red)[8][64] = (float (*)[8][64])red_raw;
  #pragma unroll
  for (int i = 0; i < 8; ++i) red[wv][i][lane] = acc[i];
  __syncthreads();

  int fi = tid >> 6, l = tid & 63;
  int ff = f0 + fi;
  int bb = b0 + l;
  float nl = 0.0f;
  if (ff < F) {
    float loc = red[0][2 * fi][l] + red[1][2 * fi][l] + red[2][2 * fi][l] + red[3][2 * fi][l]
                + cy[ff];
    float sp = red[0][2 * fi + 1][l] + red[1][2 * fi + 1][l] + red[2][2 * fi + 1][l]
               + red[3][2 * fi + 1][l] + cy[F + ff];
    float scale = softplusf_(sp) + 1e-6f;
    out_yloc[((size_t)bb * L + t) * F + ff] = loc;
    float xv = xT[((size_t)t * F + ff) * B + bb];
    float d = (xv - loc) / scale;
    nl = 0.5f * d * d + logf(scale) + 0.5f * LOG2PI_F;
  }
  waveReduceAtomicAdd(recon_acc, nl, tid);
  __syncthreads();
}

// ---------------- setup kernels ----------------

__global__ __launch_bounds__(256) void k_transpose_x(const float* __restrict__ x,
                                                     float* __restrict__ xT) {
  int idx = blockIdx.x * blockDim.x + threadIdx.x;
  int f = idx % F;
  int t = (idx / F) % L;
  int b = idx / (F * L);
  xT[(t * F + f) * B + b] = x[idx];
}

__global__ __launch_bounds__(256) void k_noise(float* __restrict__ eps_z,
                                               float* __restrict__ kld_acc,
                                               uint32_t kz0, uint32_t kz1,
                                               uint32_t kp0, uint32_t kp1) {
  int i = blockIdx.x * blockDim.x + threadIdx.x;
  uint32_t a0, a1, b0, b1;
  threefry2x32_(kz0, kz1, (uint32_t)i, (uint32_t)(i + HALF), a0, a1);
  float ez0 = bits_to_normal_(a0);
  float ez1 = bits_to_normal_(a1);
  eps_z[i] = ez0;
  eps_z[i + HALF] = ez1;
  threefry2x32_(kp0, kp1, (uint32_t)i, (uint32_t)(i + HALF), b0, b1);
  float ep0 = bits_to_normal_(b0);
  float ep1 = bits_to_normal_(b1);
  float local = -0.5f * (ez0 * ez0 + ez1 * ez1) + 0.5f * (ep0 * ep0 + ep1 * ep1);
  waveReduceAtomicAdd(kld_acc, local, threadIdx.x);
}

// A[r,:] = Whead[r,:] @ W2 ; c[r] = Whead[r,:] . b2 + bhead[r]
__global__ __launch_bounds__(256) void k_fuse(const float* __restrict__ Whead,
                                              const float* __restrict__ bhead,
                                              const float* __restrict__ W2,
                                              const float* __restrict__ b2,
                                              float* __restrict__ A,
                                              float* __restrict__ c) {
  int r = blockIdx.x;
  const float* wr = Whead + (size_t)r * D;
  for (int k = threadIdx.x; k < D; k += 256) {
    float s = 0.f;
    for (int d = 0; d < D; ++d) s = fmaf(wr[d], W2[(size_t)d * D + k], s);
    A[(size_t)r * D + k] = s;
  }
  if (threadIdx.x == 0) {
    float s = bhead[r];
    for (int d = 0; d < D; ++d) s = fmaf(wr[d], b2[d], s);
    c[r] = s;
  }
}

// ---------------- the persistent kernel ----------------

__global__ __launch_bounds__(256, 2) void k_persist(
    const float* __restrict__ xT, const float* __restrict__ eps_z,
    const float* __restrict__ phi_Wih, const float* __restrict__ phi_Whh,
    const float* __restrict__ phi_bih, const float* __restrict__ phi_bhh,
    const float* __restrict__ phi_W1, const float* __restrict__ phi_b1,
    const float* __restrict__ pu, const float* __restrict__ pw,
    const float* __restrict__ pb,
    const float* __restrict__ th_Wih, const float* __restrict__ th_Whh,
    const float* __restrict__ th_bih, const float* __restrict__ th_bhh,
    const float* __restrict__ th_W1, const float* __restrict__ th_b1,
    const float* __restrict__ Az, const float* __restrict__ cz,
    const float* __restrict__ Ay, const float* __restrict__ cy,
    float* __restrict__ out, float* __restrict__ acc,
    float* __restrict__ bufp0, float* __restrict__ bufp1,
    float* __restrict__ buft0, float* __restrict__ buft1,
    float* __restrict__ zT, float* __restrict__ z0,
    float* __restrict__ h1p, float* __restrict__ g1t,
    unsigned* __restrict__ cnt) {
  __shared__ float red[4 * 4 * 8 * 64];  // 32 KB, reused by all stages
  const int bid = blockIdx.x;
  const bool th = bid >= 256;
  const int sb = th ? bid - 256 : bid;
  const int rg = sb >> 2, bg = sb & 3;
  float* bufp[2] = {bufp0, bufp1};
  float* buft[2] = {buft0, buft1};
  unsigned phase = 0;

  for (int i = 0; i <= L; ++i) {
    // ---- interval A: phiGRU(i) || thetaGRU(i-1)+flows ----
    if (!th) {
      if (i < L)
        gru_stage<false>(xT + (size_t)i * F * B, F, 101, bufp[i & 1],
                         phi_Wih, phi_Whh, phi_bih, phi_bhh, bufp[(i + 1) & 1],
                         nullptr, nullptr, nullptr, nullptr, nullptr, rg, bg, red);
    } else if (i > 0) {
      gru_stage<true>(z0, Z, 20, buft[(i - 1) & 1],
                      th_Wih, th_Whh, th_bih, th_bhh, buft[i & 1],
                      zT, pu, pw, pb, acc, rg, bg, red);
    }
    gsync(cnt, bid, ++phase);

    // ---- interval B: phiMLP1(i) || thetaW1(i-1) ----
    if (!th) {
      if (i < L)
        lin_stage(bufp[(i + 1) & 1], H, zT, Z, phi_W1, phi_b1, h1p, 1, rg, bg, red);
    } else if (i > 0) {
      lin_stage(buft[i & 1], H, nullptr, 0, th_W1, th_b1, g1t, 1, rg, bg, red);
    }
    gsync(cnt, bid, ++phase);

    // ---- interval C: fused zhead(i) || fused yhead(i-1) ----
    if (!th) {
      if (i < L && sb < 16)
        zhead_stage(h1p, Az, cz, eps_z + (size_t)i * B * Z, z0, acc,
                    sb >> 2, sb & 3, red);
    } else if (i > 0 && sb < 40) {
      yhead_stage(g1t, Ay, cy, xT, i - 1, out, acc + 1, sb >> 2, sb & 3, red);
    }
    gsync(cnt, bid, ++phase);
  }

  if (bid == 0 && threadIdx.x == 0) {
    out[(size_t)LFB]     = gload(acc + 1);
    out[(size_t)LFB + 1] = gload(acc);
  }
}

}  // namespace

extern "C" void kernel_launch(void* const* d_in, const int* in_sizes, int n_in,
                              void* d_out, int out_size, void* d_ws, size_t ws_size,
                              hipStream_t stream) {
  const float* x        = (const float*)d_in[0];
  const float* phi_Wih  = (const float*)d_in[1];
  const float* phi_Whh  = (const float*)d_in[2];
  const float* phi_bih  = (const float*)d_in[3];
  const float* phi_bhh  = (const float*)d_in[4];
  const float* phi_W1   = (const float*)d_in[5];
  const float* phi_b1   = (const float*)d_in[6];
  const float* phi_W2   = (const float*)d_in[7];
  const float* phi_b2   = (const float*)d_in[8];
  const float* zloc_W   = (const float*)d_in[9];
  const float* zloc_b   = (const float*)d_in[10];
  const float* zscale_W = (const float*)d_in[11];
  const float* zscale_b = (const float*)d_in[12];
  const float* pu       = (const float*)d_in[13];
  const float* pw       = (const float*)d_in[14];
  const float* pb       = (const float*)d_in[15];
  const float* th_Wih   = (const float*)d_in[16];
  const float* th_Whh   = (const float*)d_in[17];
  const float* th_bih   = (const float*)d_in[18];
  const float* th_bhh   = (const float*)d_in[19];
  const float* th_W1    = (const float*)d_in[20];
  const float* th_b1    = (const float*)d_in[21];
  const float* th_W2    = (const float*)d_in[22];
  const float* th_b2    = (const float*)d_in[23];
  const float* xloc_W   = (const float*)d_in[24];
  const float* xloc_b   = (const float*)d_in[25];
  const float* xscale_W = (const float*)d_in[26];
  const float* xscale_b = (const float*)d_in[27];

  float* out = (float*)d_out;
  float* ws = (float*)d_ws;

  // workspace layout (floats)
  unsigned* cnt = (unsigned*)ws;        // 256 uints (two-level barrier counters)
  float* acc    = ws + 256;             // [0]=kld, [1]=recon
  float* eps_z  = ws + 320;             // LBZ
  float* xT     = eps_z + LBZ;          // LFB
  float* bufp0  = xT + LFB;             // HB   (zero-init: h_phi(-1))
  float* buft0  = bufp0 + HB;           // HB   (zero-init: h_theta(-1))
  float* zT     = buft0 + HB;           // ZB   (zero-init: z(-1))
  float* bufp1  = zT + ZB;              // HB
  float* buft1  = bufp1 + HB;           // HB
  float* z0     = buft1 + HB;           // ZB
  float* h1p    = z0 + ZB;              // DB
  float* g1t    = h1p + DB;             // DB
  float* Az     = g1t + DB;             // 2Z*D
  float* cz     = Az + 2 * Z * D;       // 2Z
  float* Ay     = cz + 2 * Z;           // 2F*D
  float* cy     = Ay + 2 * F * D;       // 2F

  hipMemsetAsync(ws, 0, 1344, stream);  // barrier counters + acc
  hipMemsetAsync(bufp0, 0, (size_t)(2 * HB + ZB) * sizeof(float), stream);

  uint32_t a0, a1, b0, b1;
  threefry2x32_(0u, 42u, 0u, 2u, a0, a1);
  threefry2x32_(0u, 42u, 1u, 3u, b0, b1);
  const uint32_t kz0 = a0, kz1 = b0, kp0 = a1, kp1 = b1;

  k_transpose_x<<<(B * L * F) / 256, 256, 0, stream>>>(x, xT);
  k_noise<<<HALF / 256, 256, 0, stream>>>(eps_z, acc, kz0, kz1, kp0, kp1);
  // fused head weights: z path composes with phi_W2/b2, y path with th_W2/b2
  k_fuse<<<Z, 256, 0, stream>>>(zloc_W, zloc_b, phi_W2, phi_b2, Az, cz);
  k_fuse<<<Z, 256, 0, stream>>>(zscale_W, zscale_b, phi_W2, phi_b2,
                                Az + (size_t)Z * D, cz + Z);
  k_fuse<<<F, 256, 0, stream>>>(xloc_W, xloc_b, th_W2, th_b2, Ay, cy);
  k_fuse<<<F, 256, 0, stream>>>(xscale_W, xscale_b, th_W2, th_b2,
                                Ay + (size_t)F * D, cy + F);

  k_persist<<<NBLK, 256, 0, stream>>>(
      xT, eps_z,
      phi_Wih, phi_Whh, phi_bih, phi_bhh, phi_W1, phi_b1,
      pu, pw, pb,
      th_Wih, th_Whh, th_bih, th_bhh, th_W1, th_b1,
      Az, cz, Ay, cy,
      out, acc, bufp0, bufp1, buft0, buft1, zT, z0, h1p, g1t, cnt);
}

// Round 6
// 41944.431 us; speedup vs baseline: 1.7872x; 1.0918x over previous
//
#include <hip/hip_runtime.h>
#include <stdint.h>
#include <math.h>

namespace {

constexpr int B = 256, L = 256, F = 38, H = 512, D = 512, Z = 16, NF = 20;
constexpr int NBLK = 512;          // persistent grid; 2 blocks/CU on 256 CUs
constexpr float LOG2PI_F = 1.8378770664093453f;
constexpr int LBZ = L * B * Z;
constexpr int HALF = LBZ / 2;
constexpr int HB = H * B;
constexpr int DB = D * B;
constexpr int ZB = Z * B;
constexpr int LFB = L * F * B;

// ---------------- math helpers ----------------

__device__ __forceinline__ float sigmoidf_(float x) {
  return 1.0f / (1.0f + expf(-x));
}
__device__ __forceinline__ float softplusf_(float x) {
  return fmaxf(x, 0.0f) + log1pf(expf(-fabsf(x)));
}

__device__ __forceinline__ void gAtomicAdd(float* p, float v) {
  __hip_atomic_fetch_add(p, v, __ATOMIC_RELAXED, __HIP_MEMORY_SCOPE_AGENT);
}
__device__ __forceinline__ float gload(const float* p) {
  return __hip_atomic_load(p, __ATOMIC_RELAXED, __HIP_MEMORY_SCOPE_AGENT);
}

__device__ __forceinline__ void waveReduceAtomicAdd(float* dst, float v, int tid) {
  #pragma unroll
  for (int off = 32; off > 0; off >>= 1) v += __shfl_down(v, off, 64);
  if ((tid & 63) == 0) gAtomicAdd(dst, v);
}

// MALL-coherent (sc0 sc1) batched loads: N loads in flight, ONE waitcnt.
// This is the fix for round 4's one-roundtrip-per-element atomic-load serialization.
__device__ __forceinline__ void ld4g(const float* p, float& a0, float& a1,
                                     float& a2, float& a3) {
  asm volatile(
      "global_load_dword %0, %4, off sc0 sc1\n\t"
      "global_load_dword %1, %4, off offset:1024 sc0 sc1\n\t"
      "global_load_dword %2, %4, off offset:2048 sc0 sc1\n\t"
      "global_load_dword %3, %4, off offset:3072 sc0 sc1\n\t"
      "s_waitcnt vmcnt(0)"
      : "=&v"(a0), "=&v"(a1), "=&v"(a2), "=&v"(a3)
      : "v"(p));
}
__device__ __forceinline__ void ld2g(const float* p, float& a0, float& a1) {
  asm volatile(
      "global_load_dword %0, %2, off sc0 sc1\n\t"
      "global_load_dword %1, %2, off offset:1024 sc0 sc1\n\t"
      "s_waitcnt vmcnt(0)"
      : "=&v"(a0), "=&v"(a1)
      : "v"(p));
}
__device__ __forceinline__ float ldg1(const float* p) {
  float v;
  asm volatile("global_load_dword %0, %1, off sc0 sc1\n\ts_waitcnt vmcnt(0)"
               : "=v"(v) : "v"(p));
  return v;
}
__device__ __forceinline__ void stg(float* p, float v) {
  asm volatile("global_store_dword %0, %1, off sc0 sc1"
               :: "v"(p), "v"(v) : "memory");
}

// ---------------- threefry2x32 (JAX-compatible) ----------------

__host__ __device__ inline uint32_t rotl32_(uint32_t x, int d) {
  return (x << d) | (x >> (32 - d));
}

__host__ __device__ inline void threefry2x32_(uint32_t k0, uint32_t k1,
                                              uint32_t x0, uint32_t x1,
                                              uint32_t& o0, uint32_t& o1) {
  const uint32_t ks2 = k0 ^ k1 ^ 0x1BD11BDAu;
  uint32_t v0 = x0 + k0;
  uint32_t v1 = x1 + k1;
#define TF_RND(r) { v0 += v1; v1 = rotl32_(v1, r); v1 ^= v0; }
  TF_RND(13) TF_RND(15) TF_RND(26) TF_RND(6)
  v0 += k1;  v1 += ks2 + 1u;
  TF_RND(17) TF_RND(29) TF_RND(16) TF_RND(24)
  v0 += ks2; v1 += k0 + 2u;
  TF_RND(13) TF_RND(15) TF_RND(26) TF_RND(6)
  v0 += k0;  v1 += k1 + 3u;
  TF_RND(17) TF_RND(29) TF_RND(16) TF_RND(24)
  v0 += k1;  v1 += ks2 + 4u;
  TF_RND(13) TF_RND(15) TF_RND(26) TF_RND(6)
  v0 += ks2; v1 += k0 + 5u;
#undef TF_RND
  o0 = v0; o1 = v1;
}

__device__ __forceinline__ float erfinv_f_(float x) {
  float w = -log1pf(-x * x);
  float p;
  if (w < 5.0f) {
    w -= 2.5f;
    p = 2.81022636e-08f;
    p = fmaf(p, w, 3.43273939e-07f);
    p = fmaf(p, w, -3.5233877e-06f);
    p = fmaf(p, w, -4.39150654e-06f);
    p = fmaf(p, w, 0.00021858087f);
    p = fmaf(p, w, -0.00125372503f);
    p = fmaf(p, w, -0.00417768164f);
    p = fmaf(p, w, 0.246640727f);
    p = fmaf(p, w, 1.50140941f);
  } else {
    w = sqrtf(w) - 3.0f;
    p = -0.000200214257f;
    p = fmaf(p, w, 0.000100950558f);
    p = fmaf(p, w, 0.00134934322f);
    p = fmaf(p, w, -0.00367342844f);
    p = fmaf(p, w, 0.00573950773f);
    p = fmaf(p, w, -0.0076224613f);
    p = fmaf(p, w, 0.00943887047f);
    p = fmaf(p, w, 1.00167406f);
    p = fmaf(p, w, 2.83297682f);
  }
  return p * x;
}

__device__ __forceinline__ float bits_to_normal_(uint32_t bits) {
  uint32_t m = (bits >> 9) | 0x3f800000u;
  float f = __uint_as_float(m) - 1.0f;
  float u = f * 2.0f + (-0.99999994f);
  u = fmaxf(-0.99999994f, u);
  return 1.41421356f * erfinv_f_(u);
}

__device__ __forceinline__ float flows_dev(float zv[Z], const float* __restrict__ pu,
                                           const float* __restrict__ pw,
                                           const float* __restrict__ pb) {
  float ld = 0.0f;
  for (int f = 0; f < NF; ++f) {
    const float* w = pw + f * Z;
    const float* u = pu + f * Z;
    float wn2 = 0.0f, wu = 0.0f;
    #pragma unroll
    for (int i = 0; i < Z; ++i) { wn2 = fmaf(w[i], w[i], wn2); wu = fmaf(w[i], u[i], wu); }
    float coef = (softplusf_(wu) - 1.0f - wu) / wn2;
    float a_in = pb[f];
    #pragma unroll
    for (int i = 0; i < Z; ++i) a_in = fmaf(zv[i], w[i], a_in);
    float a = tanhf(a_in);
    float uw = 0.0f;
    #pragma unroll
    for (int i = 0; i < Z; ++i) {
      float uh = fmaf(coef, w[i], u[i]);
      uw = fmaf(uh, w[i], uw);
      zv[i] = fmaf(uh, a, zv[i]);
    }
    ld += logf(fabsf(1.0f + (1.0f - a * a) * uw) + 1e-12f);
  }
  return ld;
}

// ---------------- grid barrier (round-4 proven: two-level, agent scope) ----
__device__ __forceinline__ void gsync(unsigned* cnt, int bid, unsigned phase) {
  __syncthreads();
  if (threadIdx.x == 0) {
    const int g = bid >> 6;  // 8 groups of 64 blocks
    unsigned a = __hip_atomic_fetch_add(&cnt[g * 16], 1u, __ATOMIC_RELEASE,
                                        __HIP_MEMORY_SCOPE_AGENT);
    if (a + 1u == phase * 64u)
      __hip_atomic_fetch_add(&cnt[128], 1u, __ATOMIC_RELEASE,
                             __HIP_MEMORY_SCOPE_AGENT);
    while (__hip_atomic_load(&cnt[128], __ATOMIC_RELAXED,
                             __HIP_MEMORY_SCOPE_AGENT) < phase * 8u)
      __builtin_amdgcn_s_sleep(2);
  }
  __syncthreads();
}

// ---------------- stage device functions ----------------
// Tile: 16 rows x 32 batch cols. K split 8 ways by half-wave
// (kh = 2*wave + lane_half, c = lane&31). Weights: plain cached float4 loads
// (immutable, L2-resident). Activations: ld4g (MALL, batched). LDS reduce.

template<bool THETA>
__device__ __forceinline__ void gru_stage(
    const float* __restrict__ xin,   // phi: xT_t [F][B]; theta: z0 [Z][B]
    const float* __restrict__ hT,
    const float* __restrict__ Wih, const float* __restrict__ Whh,
    const float* __restrict__ bih, const float* __restrict__ bhh,
    float* __restrict__ hout,
    float* __restrict__ zT_out, const float* __restrict__ pu,
    const float* __restrict__ pw, const float* __restrict__ pb,
    float* __restrict__ kld_acc,
    int rg, int c0, float* __restrict__ red) {
  const int tid = threadIdx.x;
  const int lane = tid & 63;
  const int kh = ((tid >> 6) << 1) | (lane >> 5);
  const int c = lane & 31;
  const int col = c0 + c;
  const int j0 = rg * 16;
  const int K1 = THETA ? Z : F;

  float aR[16], aZ[16], aNX[16], aNH[16];
  #pragma unroll
  for (int r = 0; r < 16; ++r) { aR[r] = 0.f; aZ[r] = 0.f; aNX[r] = 0.f; aNH[r] = 0.f; }

  // ---- x-part (K1 rows, strided across kh) ----
  if (THETA) {
    float zv[Z];
    #pragma unroll
    for (int q = 0; q < 4; ++q)
      ld4g(&xin[(size_t)(4 * q) * B + col], zv[4 * q], zv[4 * q + 1],
           zv[4 * q + 2], zv[4 * q + 3]);
    float ldet = flows_dev(zv, pu, pw, pb);
    for (int k = kh; k < Z; k += 8) {
      float a = zv[k];
      #pragma unroll
      for (int r = 0; r < 16; ++r) {
        aR[r]  = fmaf(Wih[(size_t)(j0 + r) * K1 + k], a, aR[r]);
        aZ[r]  = fmaf(Wih[(size_t)(H + j0 + r) * K1 + k], a, aZ[r]);
        aNX[r] = fmaf(Wih[(size_t)(2 * H + j0 + r) * K1 + k], a, aNX[r]);
      }
    }
    if (rg == 0 && kh == 0) {
      #pragma unroll
      for (int q = 0; q < Z; ++q) stg(&zT_out[(size_t)q * B + col], zv[q]);
      float s = -ldet;
      #pragma unroll
      for (int off = 16; off > 0; off >>= 1) s += __shfl_down(s, off, 32);
      if (c == 0) gAtomicAdd(kld_acc, s);
    }
  } else {
    for (int k = kh; k < F; k += 8) {
      float a = xin[(size_t)k * B + col];   // xT immutable: plain cached
      #pragma unroll
      for (int r = 0; r < 16; ++r) {
        aR[r]  = fmaf(Wih[(size_t)(j0 + r) * K1 + k], a, aR[r]);
        aZ[r]  = fmaf(Wih[(size_t)(H + j0 + r) * K1 + k], a, aZ[r]);
        aNX[r] = fmaf(Wih[(size_t)(2 * H + j0 + r) * K1 + k], a, aNX[r]);
      }
    }
  }

  // ---- h-part (64 K-rows per kh, 16 batches of 4) ----
  const float* vr = Whh + (size_t)j0 * H;
  const float* vz = Whh + (size_t)(H + j0) * H;
  const float* vn = Whh + (size_t)(2 * H + j0) * H;
  const int klo = kh * 64;
  for (int kc = klo; kc < klo + 64; kc += 4) {
    float a0, a1, a2, a3;
    ld4g(&hT[(size_t)kc * B + col], a0, a1, a2, a3);
    #pragma unroll
    for (int r = 0; r < 16; ++r) {
      float4 w;
      w = *(const float4*)&vr[(size_t)r * H + kc];
      aR[r]  = fmaf(w.x, a0, fmaf(w.y, a1, fmaf(w.z, a2, fmaf(w.w, a3, aR[r]))));
      w = *(const float4*)&vz[(size_t)r * H + kc];
      aZ[r]  = fmaf(w.x, a0, fmaf(w.y, a1, fmaf(w.z, a2, fmaf(w.w, a3, aZ[r]))));
      w = *(const float4*)&vn[(size_t)r * H + kc];
      aNH[r] = fmaf(w.x, a0, fmaf(w.y, a1, fmaf(w.z, a2, fmaf(w.w, a3, aNH[r]))));
    }
  }

  // ---- LDS reduce, pass 1 (R, Z gates) ----
  #pragma unroll
  for (int r = 0; r < 16; ++r) {
    red[(kh * 2 + 0) * 512 + r * 32 + c] = aR[r];
    red[(kh * 2 + 1) * 512 + r * 32 + c] = aZ[r];
  }
  __syncthreads();
  float rg_s[2], zg_s[2];
  #pragma unroll
  for (int p = 0; p < 2; ++p) {
    int o = tid + p * 256;
    int r = o >> 5, cc = o & 31;
    float sR = 0.f, sZ = 0.f;
    #pragma unroll
    for (int q = 0; q < 8; ++q) {
      sR += red[(q * 2 + 0) * 512 + r * 32 + cc];
      sZ += red[(q * 2 + 1) * 512 + r * 32 + cc];
    }
    int j = j0 + r;
    rg_s[p] = sigmoidf_(sR + bih[j] + bhh[j]);
    zg_s[p] = sigmoidf_(sZ + bih[H + j] + bhh[H + j]);
  }
  __syncthreads();
  // ---- pass 2 (N gates) ----
  #pragma unroll
  for (int r = 0; r < 16; ++r) {
    red[(kh * 2 + 0) * 512 + r * 32 + c] = aNX[r];
    red[(kh * 2 + 1) * 512 + r * 32 + c] = aNH[r];
  }
  __syncthreads();
  #pragma unroll
  for (int p = 0; p < 2; ++p) {
    int o = tid + p * 256;
    int r = o >> 5, cc = o & 31;
    float sNX = 0.f, sNH = 0.f;
    #pragma unroll
    for (int q = 0; q < 8; ++q) {
      sNX += red[(q * 2 + 0) * 512 + r * 32 + cc];
      sNH += red[(q * 2 + 1) * 512 + r * 32 + cc];
    }
    int j = j0 + r;
    float ng = tanhf(sNX + bih[2 * H + j] + rg_s[p] * (sNH + bhh[2 * H + j]));
    float hp = ldg1(&hT[(size_t)j * B + c0 + cc]);
    stg(&hout[(size_t)j * B + c0 + cc], (1.0f - zg_s[p]) * ng + zg_s[p] * hp);
  }
}

__device__ __forceinline__ void lin_stage(
    const float* __restrict__ A1, const float* __restrict__ zTail,
    const float* __restrict__ W, int Kv, const float* __restrict__ bias,
    float* __restrict__ outp, int relu, int rg, int c0,
    float* __restrict__ red) {
  const int tid = threadIdx.x;
  const int lane = tid & 63;
  const int kh = ((tid >> 6) << 1) | (lane >> 5);
  const int c = lane & 31;
  const int col = c0 + c;
  const int j0 = rg * 16;

  float acc[16];
  #pragma unroll
  for (int r = 0; r < 16; ++r) acc[r] = 0.f;

  const float* wb = W + (size_t)j0 * Kv;
  const int klo = kh * 64;
  for (int kc = klo; kc < klo + 64; kc += 4) {
    float a0, a1, a2, a3;
    ld4g(&A1[(size_t)kc * B + col], a0, a1, a2, a3);
    #pragma unroll
    for (int r = 0; r < 16; ++r) {
      float4 w = *(const float4*)&wb[(size_t)r * Kv + kc];
      acc[r] = fmaf(w.x, a0, fmaf(w.y, a1, fmaf(w.z, a2, fmaf(w.w, a3, acc[r]))));
    }
  }
  if (zTail != nullptr) {   // 16 z rows, 2 per kh
    int k0 = kh * 2;
    float a0, a1;
    ld2g(&zTail[(size_t)k0 * B + col], a0, a1);
    #pragma unroll
    for (int r = 0; r < 16; ++r) {
      acc[r] = fmaf(wb[(size_t)r * Kv + 512 + k0], a0, acc[r]);
      acc[r] = fmaf(wb[(size_t)r * Kv + 512 + k0 + 1], a1, acc[r]);
    }
  }

  #pragma unroll
  for (int r = 0; r < 16; ++r) red[kh * 512 + r * 32 + c] = acc[r];
  __syncthreads();
  #pragma unroll
  for (int p = 0; p < 2; ++p) {
    int o = tid + p * 256;
    int r = o >> 5, cc = o & 31;
    float s = bias[j0 + r];
    #pragma unroll
    for (int q = 0; q < 8; ++q) s += red[q * 512 + r * 32 + cc];
    if (relu) s = fmaxf(s, 0.f);
    stg(&outp[(size_t)(j0 + r) * B + c0 + cc], s);
  }
}

// z head fused with phi_W2 (Az rows interleaved loc/scale)
__device__ __forceinline__ void zhead_stage(
    const float* __restrict__ h1T, const float* __restrict__ Az,
    const float* __restrict__ cz, const float* __restrict__ eps_t,
    float* __restrict__ z0T, float* __restrict__ kld_acc,
    int rg2, int c0, float* __restrict__ red) {
  const int tid = threadIdx.x;
  const int lane = tid & 63;
  const int kh = ((tid >> 6) << 1) | (lane >> 5);
  const int c = lane & 31;
  const int col = c0 + c;
  const int j0 = rg2 * 16;

  float acc[16];
  #pragma unroll
  for (int r = 0; r < 16; ++r) acc[r] = 0.f;
  const float* wb = Az + (size_t)j0 * 512;
  const int klo = kh * 64;
  for (int kc = klo; kc < klo + 64; kc += 4) {
    float a0, a1, a2, a3;
    ld4g(&h1T[(size_t)kc * B + col], a0, a1, a2, a3);
    #pragma unroll
    for (int r = 0; r < 16; ++r) {
      float4 w = *(const float4*)&wb[(size_t)r * 512 + kc];
      acc[r] = fmaf(w.x, a0, fmaf(w.y, a1, fmaf(w.z, a2, fmaf(w.w, a3, acc[r]))));
    }
  }
  #pragma unroll
  for (int r = 0; r < 16; ++r) red[kh * 512 + r * 32 + c] = acc[r];
  __syncthreads();
  {
    int qi = tid >> 5, cc = tid & 31;       // 8 z-pairs x 32 cols
    int z = rg2 * 8 + qi;
    float sl = cz[2 * z], ss = cz[2 * z + 1];
    #pragma unroll
    for (int q = 0; q < 8; ++q) {
      sl += red[q * 512 + (2 * qi) * 32 + cc];
      ss += red[q * 512 + (2 * qi + 1) * 32 + cc];
    }
    float scale = softplusf_(ss) + 1e-6f;
    float ez = eps_t[(size_t)(c0 + cc) * Z + z];
    stg(&z0T[(size_t)z * B + c0 + cc], sl + scale * ez);
    waveReduceAtomicAdd(kld_acc, -logf(scale), tid);
  }
}

// y head fused with th_W2 (Ay rows interleaved loc/scale, padded to 80)
__device__ __forceinline__ void yhead_stage(
    const float* __restrict__ g1T, const float* __restrict__ Ay,
    const float* __restrict__ cy, const float* __restrict__ xT, int t,
    float* __restrict__ out_yloc, float* __restrict__ recon_acc,
    int yt, int c0, float* __restrict__ red) {
  const int tid = threadIdx.x;
  const int lane = tid & 63;
  const int kh = ((tid >> 6) << 1) | (lane >> 5);
  const int c = lane & 31;
  const int col = c0 + c;
  const int j0 = yt * 16;

  float acc[16];
  #pragma unroll
  for (int r = 0; r < 16; ++r) acc[r] = 0.f;
  const float* wb = Ay + (size_t)j0 * 512;
  const int klo = kh * 64;
  for (int kc = klo; kc < klo + 64; kc += 4) {
    float a0, a1, a2, a3;
    ld4g(&g1T[(size_t)kc * B + col], a0, a1, a2, a3);
    #pragma unroll
    for (int r = 0; r < 16; ++r) {
      float4 w = *(const float4*)&wb[(size_t)r * 512 + kc];
      acc[r] = fmaf(w.x, a0, fmaf(w.y, a1, fmaf(w.z, a2, fmaf(w.w, a3, acc[r]))));
    }
  }
  #pragma unroll
  for (int r = 0; r < 16; ++r) red[kh * 512 + r * 32 + c] = acc[r];
  __syncthreads();
  {
    int qi = tid >> 5, cc = tid & 31;
    int f = yt * 8 + qi;
    float nl = 0.0f;
    if (f < F) {
      float loc = cy[2 * f], sp = cy[2 * f + 1];
      #pragma unroll
      for (int q = 0; q < 8; ++q) {
        loc += red[q * 512 + (2 * qi) * 32 + cc];
        sp  += red[q * 512 + (2 * qi + 1) * 32 + cc];
      }
      float scale = softplusf_(sp) + 1e-6f;
      int b = c0 + cc;
      out_yloc[((size_t)b * L + t) * F + f] = loc;
      float xv = xT[((size_t)t * F + f) * B + b];
      float dd = (xv - loc) / scale;
      nl = 0.5f * dd * dd + logf(scale) + 0.5f * LOG2PI_F;
    }
    waveReduceAtomicAdd(recon_acc, nl, tid);
  }
}

// ---------------- setup kernels ----------------

__global__ __launch_bounds__(256) void k_transpose_x(const float* __restrict__ x,
                                                     float* __restrict__ xT) {
  int idx = blockIdx.x * blockDim.x + threadIdx.x;
  int f = idx % F;
  int t = (idx / F) % L;
  int b = idx / (F * L);
  xT[(t * F + f) * B + b] = x[idx];
}

__global__ __launch_bounds__(256) void k_noise(float* __restrict__ eps_z,
                                               float* __restrict__ kld_acc,
                                               uint32_t kz0, uint32_t kz1,
                                               uint32_t kp0, uint32_t kp1) {
  int i = blockIdx.x * blockDim.x + threadIdx.x;
  uint32_t a0, a1, b0, b1;
  threefry2x32_(kz0, kz1, (uint32_t)i, (uint32_t)(i + HALF), a0, a1);
  float ez0 = bits_to_normal_(a0);
  float ez1 = bits_to_normal_(a1);
  eps_z[i] = ez0;
  eps_z[i + HALF] = ez1;
  threefry2x32_(kp0, kp1, (uint32_t)i, (uint32_t)(i + HALF), b0, b1);
  float ep0 = bits_to_normal_(b0);
  float ep1 = bits_to_normal_(b1);
  float local = -0.5f * (ez0 * ez0 + ez1 * ez1) + 0.5f * (ep0 * ep0 + ep1 * ep1);
  waveReduceAtomicAdd(kld_acc, local, threadIdx.x);
}

// A[(r*2+radd),:] = Whead[r,:] @ W2 ; c[r*2+radd] = Whead[r,:].b2 + bhead[r]
__global__ __launch_bounds__(256) void k_fuse(const float* __restrict__ Whead,
                                              const float* __restrict__ bhead,
                                              const float* __restrict__ W2,
                                              const float* __restrict__ b2,
                                              float* __restrict__ A,
                                              float* __restrict__ c, int radd) {
  int r = blockIdx.x;
  const float* wr = Whead + (size_t)r * D;
  for (int k = threadIdx.x; k < D; k += 256) {
    float s = 0.f;
    for (int d = 0; d < D; ++d) s = fmaf(wr[d], W2[(size_t)d * D + k], s);
    A[(size_t)(r * 2 + radd) * D + k] = s;
  }
  if (threadIdx.x == 0) {
    float s = bhead[r];
    for (int d = 0; d < D; ++d) s = fmaf(wr[d], b2[d], s);
    c[r * 2 + radd] = s;
  }
}

// ---------------- the persistent kernel ----------------

__global__ __launch_bounds__(256, 2) void k_persist(
    const float* __restrict__ xT, const float* __restrict__ eps_z,
    const float* __restrict__ phi_Wih, const float* __restrict__ phi_Whh,
    const float* __restrict__ phi_bih, const float* __restrict__ phi_bhh,
    const float* __restrict__ phi_W1, const float* __restrict__ phi_b1,
    const float* __restrict__ pu, const float* __restrict__ pw,
    const float* __restrict__ pb,
    const float* __restrict__ th_Wih, const float* __restrict__ th_Whh,
    const float* __restrict__ th_bih, const float* __restrict__ th_bhh,
    const float* __restrict__ th_W1, const float* __restrict__ th_b1,
    const float* __restrict__ Az, const float* __restrict__ cz,
    const float* __restrict__ Ay, const float* __restrict__ cy,
    float* __restrict__ out, float* __restrict__ acc,
    float* __restrict__ bufp0, float* __restrict__ bufp1,
    float* __restrict__ buft0, float* __restrict__ buft1,
    float* __restrict__ zT, float* __restrict__ z0,
    float* __restrict__ h1p, float* __restrict__ g1t,
    unsigned* __restrict__ cnt) {
  __shared__ float red[8192];   // 32 KB, reused by all stages
  const int bid = blockIdx.x;
  const bool th = bid >= 256;
  const int sb = th ? bid - 256 : bid;
  const int rg = sb >> 3, cg = sb & 7;
  const int c0 = cg * 32;
  float* bufp[2] = {bufp0, bufp1};
  float* buft[2] = {buft0, buft1};
  unsigned phase = 0;

  for (int i = 0; i <= L; ++i) {
    float* ph_in  = bufp[i & 1];
    float* ph_out = bufp[(i + 1) & 1];
    float* th_in  = buft[(i + 1) & 1];
    float* th_out = buft[i & 1];

    // ---- phase A: phiGRU(i) || thetaGRU(i-1)+flows ----
    if (!th) {
      if (i < L)
        gru_stage<false>(xT + (size_t)i * F * B, ph_in, phi_Wih, phi_Whh,
                         phi_bih, phi_bhh, ph_out, nullptr, nullptr, nullptr,
                         nullptr, nullptr, rg, c0, red);
    } else if (i > 0) {
      gru_stage<true>(z0, th_in, th_Wih, th_Whh, th_bih, th_bhh, th_out,
                      zT, pu, pw, pb, acc, rg, c0, red);
    }
    gsync(cnt, bid, ++phase);

    // ---- phase B: phiMLP1(i) || thetaW1(i-1) ----
    if (!th) {
      if (i < L)
        lin_stage(ph_out, zT, phi_W1, 528, phi_b1, h1p, 1, rg, c0, red);
    } else if (i > 0) {
      lin_stage(th_out, nullptr, th_W1, 512, th_b1, g1t, 1, rg, c0, red);
    }
    gsync(cnt, bid, ++phase);

    // ---- phase C: fused zhead(i) || fused yhead(i-1) ----
    if (!th) {
      if (i < L && sb < 16)
        zhead_stage(h1p, Az, cz, eps_z + (size_t)i * B * Z, z0, acc,
                    sb >> 3, (sb & 7) * 32, red);
    } else if (i > 0 && sb < 40) {
      yhead_stage(g1t, Ay, cy, xT, i - 1, out, acc + 1,
                  sb >> 3, (sb & 7) * 32, red);
    }
    gsync(cnt, bid, ++phase);
  }

  if (bid == 0 && threadIdx.x == 0) {
    out[(size_t)LFB]     = gload(acc + 1);
    out[(size_t)LFB + 1] = gload(acc);
  }
}

}  // namespace

extern "C" void kernel_launch(void* const* d_in, const int* in_sizes, int n_in,
                              void* d_out, int out_size, void* d_ws, size_t ws_size,
                              hipStream_t stream) {
  const float* x        = (const float*)d_in[0];
  const float* phi_Wih  = (const float*)d_in[1];
  const float* phi_Whh  = (const float*)d_in[2];
  const float* phi_bih  = (const float*)d_in[3];
  const float* phi_bhh  = (const float*)d_in[4];
  const float* phi_W1   = (const float*)d_in[5];
  const float* phi_b1   = (const float*)d_in[6];
  const float* phi_W2   = (const float*)d_in[7];
  const float* phi_b2   = (const float*)d_in[8];
  const float* zloc_W   = (const float*)d_in[9];
  const float* zloc_b   = (const float*)d_in[10];
  const float* zscale_W = (const float*)d_in[11];
  const float* zscale_b = (const float*)d_in[12];
  const float* pu       = (const float*)d_in[13];
  const float* pw       = (const float*)d_in[14];
  const float* pb       = (const float*)d_in[15];
  const float* th_Wih   = (const float*)d_in[16];
  const float* th_Whh   = (const float*)d_in[17];
  const float* th_bih   = (const float*)d_in[18];
  const float* th_bhh   = (const float*)d_in[19];
  const float* th_W1    = (const float*)d_in[20];
  const float* th_b1    = (const float*)d_in[21];
  const float* th_W2    = (const float*)d_in[22];
  const float* th_b2    = (const float*)d_in[23];
  const float* xloc_W   = (const float*)d_in[24];
  const float* xloc_b   = (const float*)d_in[25];
  const float* xscale_W = (const float*)d_in[26];
  const float* xscale_b = (const float*)d_in[27];

  float* out = (float*)d_out;
  float* ws = (float*)d_ws;

  // workspace layout (floats)
  unsigned* cnt = (unsigned*)ws;        // 256 uints (two-level barrier counters)
  float* acc    = ws + 256;             // [0]=kld, [1]=recon
  float* eps_z  = ws + 320;             // LBZ
  float* xT     = eps_z + LBZ;          // LFB
  float* bufp0  = xT + LFB;             // HB  (zero: h_phi(-1))
  float* buft0  = bufp0 + HB;           // HB  (zero: h_th(-1))
  float* zT     = buft0 + HB;           // ZB  (zero: z(-1))
  float* bufp1  = zT + ZB;              // HB
  float* buft1  = bufp1 + HB;           // HB
  float* z0     = buft1 + HB;           // ZB
  float* h1p    = z0 + ZB;              // DB
  float* g1t    = h1p + DB;             // DB
  float* Az     = g1t + DB;             // 32*512 (interleaved loc/scale rows)
  float* cz     = Az + 32 * 512;        // 64
  float* Ay     = cz + 64;              // 80*512 (rows >=76 unused)
  float* cy     = Ay + 80 * 512;        // 160

  hipMemsetAsync(ws, 0, 1344, stream);  // barrier counters + acc
  hipMemsetAsync(bufp0, 0, (size_t)(2 * HB + ZB) * sizeof(float), stream);

  uint32_t a0, a1, b0, b1;
  threefry2x32_(0u, 42u, 0u, 2u, a0, a1);
  threefry2x32_(0u, 42u, 1u, 3u, b0, b1);
  const uint32_t kz0 = a0, kz1 = b0, kp0 = a1, kp1 = b1;

  k_transpose_x<<<(B * L * F) / 256, 256, 0, stream>>>(x, xT);
  k_noise<<<HALF / 256, 256, 0, stream>>>(eps_z, acc, kz0, kz1, kp0, kp1);
  // head fusion: z path composes with phi_W2/b2, y path with th_W2/b2
  k_fuse<<<Z, 256, 0, stream>>>(zloc_W, zloc_b, phi_W2, phi_b2, Az, cz, 0);
  k_fuse<<<Z, 256, 0, stream>>>(zscale_W, zscale_b, phi_W2, phi_b2, Az, cz, 1);
  k_fuse<<<F, 256, 0, stream>>>(xloc_W, xloc_b, th_W2, th_b2, Ay, cy, 0);
  k_fuse<<<F, 256, 0, stream>>>(xscale_W, xscale_b, th_W2, th_b2, Ay, cy, 1);

  k_persist<<<NBLK, 256, 0, stream>>>(
      xT, eps_z,
      phi_Wih, phi_Whh, phi_bih, phi_bhh, phi_W1, phi_b1,
      pu, pw, pb,
      th_Wih, th_Whh, th_bih, th_bhh, th_W1, th_b1,
      Az, cz, Ay, cy,
      out, acc, bufp0, bufp1, buft0, buft1, zT, z0, h1p, g1t, cnt);
}